// Round 6
// baseline (333.142 us; speedup 1.0000x reference)
//
#include <hip/hip_runtime.h>
#include <math.h>

#define NN 50000
#define FIN 128
#define EE 800000            // CSR holds only real edges; self-loops handled analytically
#define ETEST 100000
#define NEG_SLOPE 0.2f
#define SCAN_B 196           // ceil(NN/256)
#define XP 68                // LDS pitch for transposed x tile (16B-aligned quads)
#define UG 16                // gather unroll width (predicated)

static inline int cdiv(long long a, int b) { return (int)((a + b - 1) / b); }

// ---------------- CSR build (by dst, real edges only), rebuilt every call ----------------

__global__ void hist_kernel(const int* __restrict__ ei, int* __restrict__ deg) {
    int e = blockIdx.x * 256 + threadIdx.x;
    if (e >= EE) return;
    atomicAdd(&deg[ei[EE + e]], 1);
}

__global__ void block_sums(const int* __restrict__ deg, int* __restrict__ bsum) {
    int idx = blockIdx.x * 256 + threadIdx.x;
    int v = (idx < NN) ? deg[idx] : 0;
#pragma unroll
    for (int off = 32; off >= 1; off >>= 1) v += __shfl_xor(v, off, 64);
    __shared__ int ws[4];
    if ((threadIdx.x & 63) == 0) ws[threadIdx.x >> 6] = v;
    __syncthreads();
    if (threadIdx.x == 0) bsum[blockIdx.x] = ws[0] + ws[1] + ws[2] + ws[3];
}

__global__ void scan_bsums(const int* __restrict__ bsum, int* __restrict__ boff,
                           int* __restrict__ rowptr) {
    __shared__ int s[256];
    int t = threadIdx.x;
    int v = (t < SCAN_B) ? bsum[t] : 0;
    s[t] = v;
    __syncthreads();
#pragma unroll
    for (int off = 1; off < 256; off <<= 1) {
        int u = (t >= off) ? s[t - off] : 0;
        __syncthreads();
        s[t] += u;
        __syncthreads();
    }
    if (t < SCAN_B) boff[t] = s[t] - v;   // exclusive
    if (t == 0) rowptr[NN] = EE;
}

__global__ void scan_final(const int* __restrict__ deg, const int* __restrict__ boff,
                           int* __restrict__ rowptr, int* __restrict__ cursor) {
    __shared__ int s[256];
    int t = threadIdx.x;
    int idx = blockIdx.x * 256 + t;
    int v = (idx < NN) ? deg[idx] : 0;
    s[t] = v;
    __syncthreads();
#pragma unroll
    for (int off = 1; off < 256; off <<= 1) {
        int u = (t >= off) ? s[t - off] : 0;
        __syncthreads();
        s[t] += u;
        __syncthreads();
    }
    if (idx < NN) {
        int excl = boff[blockIdx.x] + s[t] - v;
        rowptr[idx] = excl;
        cursor[idx] = excl;
    }
}

__global__ void fill_kernel(const int* __restrict__ ei, int* __restrict__ cursor,
                            int* __restrict__ col) {
    int e = blockIdx.x * 256 + threadIdx.x;
    if (e >= EE) return;
    int src = ei[e], dst = ei[EE + e];
    int pos = atomicAdd(&cursor[dst], 1);
    __builtin_nontemporal_store(src, &col[pos]);   // bypass L2: kill cross-XCD line ping-pong
}

// ---------------- Register-tiled GEMMs (64x64 tile, 4x4 acc per lane) ----------------

// x[NN,128] @ W[128,64] -> h; fused per-head dots (H=8,C=8)
__global__ void __launch_bounds__(256) gemm1_kernel(
        const float* __restrict__ x, const float* __restrict__ W,
        const float* __restrict__ att_src, const float* __restrict__ att_dst,
        float* __restrict__ h, float* __restrict__ a_src, float* __restrict__ a_dst) {
    __shared__ __align__(16) float Ws[FIN * 64];     // 32 KB
    __shared__ __align__(16) float xs[32 * XP];      // 8.7 KB, transposed chunk [k][r]
    int tid = threadIdx.x;
    for (int i = tid; i < FIN * 64 / 4; i += 256)
        ((float4*)Ws)[i] = ((const float4*)W)[i];
    int B = blockIdx.x * 64;
    int wave = tid >> 6, lane = tid & 63;
    int rg = lane >> 4, cg = lane & 15;
    int rbase = wave * 16 + rg * 4;
    float acc[4][4] = {};
    for (int kc = 0; kc < FIN; kc += 32) {
        __syncthreads();
#pragma unroll
        for (int p = 0; p < 2; ++p) {
            int idx = p * 256 + tid;            // 0..511
            int r = idx >> 3;                   // 0..63
            int m = idx & 7;
            int row = B + r;
            float4 v = (row < NN) ? ((const float4*)(x + (size_t)row * FIN + kc))[m]
                                  : make_float4(0.f, 0.f, 0.f, 0.f);
            int c4 = m << 2;
            xs[(c4 + 0) * XP + r] = v.x;
            xs[(c4 + 1) * XP + r] = v.y;
            xs[(c4 + 2) * XP + r] = v.z;
            xs[(c4 + 3) * XP + r] = v.w;
        }
        __syncthreads();
#pragma unroll 4
        for (int k = 0; k < 32; ++k) {
            float4 w4 = *(const float4*)&Ws[(kc + k) * 64 + cg * 4];
            float4 x4 = *(const float4*)&xs[k * XP + rbase];
            acc[0][0] = fmaf(x4.x, w4.x, acc[0][0]); acc[0][1] = fmaf(x4.x, w4.y, acc[0][1]);
            acc[0][2] = fmaf(x4.x, w4.z, acc[0][2]); acc[0][3] = fmaf(x4.x, w4.w, acc[0][3]);
            acc[1][0] = fmaf(x4.y, w4.x, acc[1][0]); acc[1][1] = fmaf(x4.y, w4.y, acc[1][1]);
            acc[1][2] = fmaf(x4.y, w4.z, acc[1][2]); acc[1][3] = fmaf(x4.y, w4.w, acc[1][3]);
            acc[2][0] = fmaf(x4.z, w4.x, acc[2][0]); acc[2][1] = fmaf(x4.z, w4.y, acc[2][1]);
            acc[2][2] = fmaf(x4.z, w4.z, acc[2][2]); acc[2][3] = fmaf(x4.z, w4.w, acc[2][3]);
            acc[3][0] = fmaf(x4.w, w4.x, acc[3][0]); acc[3][1] = fmaf(x4.w, w4.y, acc[3][1]);
            acc[3][2] = fmaf(x4.w, w4.z, acc[3][2]); acc[3][3] = fmaf(x4.w, w4.w, acc[3][3]);
        }
    }
    float as0 = att_src[4 * cg + 0], as1 = att_src[4 * cg + 1],
          as2 = att_src[4 * cg + 2], as3 = att_src[4 * cg + 3];
    float ad0 = att_dst[4 * cg + 0], ad1 = att_dst[4 * cg + 1],
          ad2 = att_dst[4 * cg + 2], ad3 = att_dst[4 * cg + 3];
#pragma unroll
    for (int j = 0; j < 4; ++j) {
        int row = B + rbase + j;
        if (row >= NN) continue;
        float4 hv = make_float4(acc[j][0], acc[j][1], acc[j][2], acc[j][3]);
        *(float4*)(h + (size_t)row * 64 + cg * 4) = hv;
        float ps = fmaf(hv.x, as0, fmaf(hv.y, as1, fmaf(hv.z, as2, hv.w * as3)));
        float pd = fmaf(hv.x, ad0, fmaf(hv.y, ad1, fmaf(hv.z, ad2, hv.w * ad3)));
        ps += __shfl_xor(ps, 1, 64);
        pd += __shfl_xor(pd, 1, 64);
        if ((cg & 1) == 0) {
            a_src[row * 8 + (cg >> 1)] = ps;
            a_dst[row * 8 + (cg >> 1)] = pd;
        }
    }
}

// z[NN,64] @ W[64,64] -> h; fused dots (H=1,C=64)
__global__ void __launch_bounds__(256) gemm2_kernel(
        const float* __restrict__ z, const float* __restrict__ W,
        const float* __restrict__ att_src, const float* __restrict__ att_dst,
        float* __restrict__ h, float* __restrict__ a_src, float* __restrict__ a_dst) {
    __shared__ __align__(16) float Ws[64 * 64];      // 16 KB
    __shared__ __align__(16) float xs[64 * XP];      // 17.4 KB, transposed [k][r]
    int tid = threadIdx.x;
    for (int i = tid; i < 64 * 64 / 4; i += 256)
        ((float4*)Ws)[i] = ((const float4*)W)[i];
    int B = blockIdx.x * 64;
#pragma unroll
    for (int p = 0; p < 4; ++p) {
        int idx = p * 256 + tid;                // 0..1023
        int r = idx >> 4;
        int m = idx & 15;
        int row = B + r;
        float4 v = (row < NN) ? ((const float4*)(z + (size_t)row * 64))[m]
                              : make_float4(0.f, 0.f, 0.f, 0.f);
        int c4 = m << 2;
        xs[(c4 + 0) * XP + r] = v.x;
        xs[(c4 + 1) * XP + r] = v.y;
        xs[(c4 + 2) * XP + r] = v.z;
        xs[(c4 + 3) * XP + r] = v.w;
    }
    int wave = tid >> 6, lane = tid & 63;
    int rg = lane >> 4, cg = lane & 15;
    int rbase = wave * 16 + rg * 4;
    float acc[4][4] = {};
    __syncthreads();
#pragma unroll 4
    for (int k = 0; k < 64; ++k) {
        float4 w4 = *(const float4*)&Ws[k * 64 + cg * 4];
        float4 x4 = *(const float4*)&xs[k * XP + rbase];
        acc[0][0] = fmaf(x4.x, w4.x, acc[0][0]); acc[0][1] = fmaf(x4.x, w4.y, acc[0][1]);
        acc[0][2] = fmaf(x4.x, w4.z, acc[0][2]); acc[0][3] = fmaf(x4.x, w4.w, acc[0][3]);
        acc[1][0] = fmaf(x4.y, w4.x, acc[1][0]); acc[1][1] = fmaf(x4.y, w4.y, acc[1][1]);
        acc[1][2] = fmaf(x4.y, w4.z, acc[1][2]); acc[1][3] = fmaf(x4.y, w4.w, acc[1][3]);
        acc[2][0] = fmaf(x4.z, w4.x, acc[2][0]); acc[2][1] = fmaf(x4.z, w4.y, acc[2][1]);
        acc[2][2] = fmaf(x4.z, w4.z, acc[2][2]); acc[2][3] = fmaf(x4.z, w4.w, acc[2][3]);
        acc[3][0] = fmaf(x4.w, w4.x, acc[3][0]); acc[3][1] = fmaf(x4.w, w4.y, acc[3][1]);
        acc[3][2] = fmaf(x4.w, w4.z, acc[3][2]); acc[3][3] = fmaf(x4.w, w4.w, acc[3][3]);
    }
    float as0 = att_src[4 * cg + 0], as1 = att_src[4 * cg + 1],
          as2 = att_src[4 * cg + 2], as3 = att_src[4 * cg + 3];
    float ad0 = att_dst[4 * cg + 0], ad1 = att_dst[4 * cg + 1],
          ad2 = att_dst[4 * cg + 2], ad3 = att_dst[4 * cg + 3];
#pragma unroll
    for (int j = 0; j < 4; ++j) {
        int row = B + rbase + j;
        if (row >= NN) continue;
        float4 hv = make_float4(acc[j][0], acc[j][1], acc[j][2], acc[j][3]);
        *(float4*)(h + (size_t)row * 64 + cg * 4) = hv;
        float ps = fmaf(hv.x, as0, fmaf(hv.y, as1, fmaf(hv.z, as2, hv.w * as3)));
        float pd = fmaf(hv.x, ad0, fmaf(hv.y, ad1, fmaf(hv.z, ad2, hv.w * ad3)));
#pragma unroll
        for (int off = 8; off >= 1; off >>= 1) {
            ps += __shfl_xor(ps, off, 64);
            pd += __shfl_xor(pd, off, 64);
        }
        if (cg == 0) { a_src[row] = ps; a_dst[row] = pd; }
    }
}

// ---------------- Fused GAT aggregation: predicated 16-wide, self-loop analytic ----------------

__device__ __forceinline__ float lrelu(float a) { return a > 0.f ? a : NEG_SLOPE * a; }

// Layer 1: H=8, C=8. One wave per dst node; lane = h*8+c.
__global__ void gat1_gather(const int* __restrict__ rowptr, const int* __restrict__ col,
                            const float* __restrict__ asrc, const float* __restrict__ adst,
                            const float* __restrict__ hfeat, const float* __restrict__ bias,
                            float* __restrict__ z1) {
    int v = blockIdx.x * 4 + (threadIdx.x >> 6);
    if (v >= NN) return;
    int lane = threadIdx.x & 63;
    int h = lane >> 3;
    int beg = rowptr[v], end = rowptr[v + 1];
    float ad = adst[v * 8 + h];
    // self-loop term (coalesced, off the gather chain)
    float eself = __expf(lrelu(asrc[v * 8 + h] + ad));
    float den = eself;
    float acc = eself * hfeat[(size_t)v * 64 + lane];
    for (int i = beg; i < end; i += UG) {
        int lim = end - i;
        int s[UG]; float a[UG], f[UG];
#pragma unroll
        for (int u = 0; u < UG; ++u) {
            int idx = (u < lim) ? i + u : end - 1;   // clamped lanes: broadcast line
            s[u] = col[idx];
        }
#pragma unroll
        for (int u = 0; u < UG; ++u) a[u] = asrc[s[u] * 8 + h] + ad;
#pragma unroll
        for (int u = 0; u < UG; ++u) f[u] = hfeat[(size_t)s[u] * 64 + lane];
#pragma unroll
        for (int u = 0; u < UG; ++u) {
            float e = (u < lim) ? __expf(lrelu(a[u])) : 0.f;
            den += e;
            acc = fmaf(e, f[u], acc);
        }
    }
    float o = acc / fmaxf(den, 1e-16f) + bias[lane];
    z1[(size_t)v * 64 + lane] = o > 0.f ? o : expm1f(o);   // fused ELU
}

// Layer 2: H=1, C=64.
__global__ void gat2_gather(const int* __restrict__ rowptr, const int* __restrict__ col,
                            const float* __restrict__ asrc, const float* __restrict__ adst,
                            const float* __restrict__ hfeat, const float* __restrict__ bias,
                            float* __restrict__ z2) {
    int v = blockIdx.x * 4 + (threadIdx.x >> 6);
    if (v >= NN) return;
    int lane = threadIdx.x & 63;
    int beg = rowptr[v], end = rowptr[v + 1];
    float ad = adst[v];
    float eself = __expf(lrelu(asrc[v] + ad));
    float den = eself;
    float acc = eself * hfeat[(size_t)v * 64 + lane];
    for (int i = beg; i < end; i += UG) {
        int lim = end - i;
        int s[UG]; float a[UG], f[UG];
#pragma unroll
        for (int u = 0; u < UG; ++u) {
            int idx = (u < lim) ? i + u : end - 1;
            s[u] = col[idx];
        }
#pragma unroll
        for (int u = 0; u < UG; ++u) a[u] = asrc[s[u]] + ad;
#pragma unroll
        for (int u = 0; u < UG; ++u) f[u] = hfeat[(size_t)s[u] * 64 + lane];
#pragma unroll
        for (int u = 0; u < UG; ++u) {
            float e = (u < lim) ? __expf(lrelu(a[u])) : 0.f;
            den += e;
            acc = fmaf(e, f[u], acc);
        }
    }
    z2[(size_t)v * 64 + lane] = acc / fmaxf(den, 1e-16f) + bias[lane];
}

// logits[i] = dot64(z2[a], z2[b]); 16 lanes per logit, float4 loads
__global__ void logits_kernel(const int* __restrict__ pos, const int* __restrict__ neg,
                              const float* __restrict__ z2, float* __restrict__ out) {
    int t = blockIdx.x * 256 + threadIdx.x;
    int i = t >> 4;
    if (i >= 2 * ETEST) return;
    int sub = t & 15;
    int a, b;
    if (i < ETEST) { a = pos[i]; b = pos[ETEST + i]; }
    else           { a = neg[i - ETEST]; b = neg[i]; }
    float4 va = ((const float4*)(z2 + (size_t)a * 64))[sub];
    float4 vb = ((const float4*)(z2 + (size_t)b * 64))[sub];
    float p = fmaf(va.x, vb.x, fmaf(va.y, vb.y, fmaf(va.z, vb.z, va.w * vb.w)));
#pragma unroll
    for (int off = 8; off >= 1; off >>= 1) p += __shfl_xor(p, off, 64);
    if (sub == 0) out[i] = p;
}

extern "C" void kernel_launch(void* const* d_in, const int* in_sizes, int n_in,
                              void* d_out, int out_size, void* d_ws, size_t ws_size,
                              hipStream_t stream) {
    const float* x    = (const float*)d_in[0];
    const int*   ei   = (const int*)d_in[1];
    const int*   pos  = (const int*)d_in[2];
    const int*   neg  = (const int*)d_in[3];
    const float* W1   = (const float*)d_in[4];
    const float* asr1 = (const float*)d_in[5];
    const float* ads1 = (const float*)d_in[6];
    const float* b1   = (const float*)d_in[7];
    const float* W2   = (const float*)d_in[8];
    const float* asr2 = (const float*)d_in[9];
    const float* ads2 = (const float*)d_in[10];
    const float* b2   = (const float*)d_in[11];
    float* out = (float*)d_out;

    float* ws  = (float*)d_ws;
    float* h1  = ws;                       // NN*64 (h of layer1, reused as h of layer2)
    float* z1  = h1 + (size_t)NN * 64;     // NN*64
    float* z2  = z1 + (size_t)NN * 64;     // NN*64
    float* as1 = z2 + (size_t)NN * 64;     // NN*8
    float* ad1 = as1 + (size_t)NN * 8;     // NN*8
    float* as2 = ad1 + (size_t)NN * 8;     // NN
    float* ad2 = as2 + NN;                 // NN
    int* deg    = (int*)(ad2 + NN);        // NN
    int* rowptr = deg + NN;                // NN+1
    int* cursor = rowptr + NN + 1;         // NN
    int* bsum   = cursor + NN;             // SCAN_B
    int* boff   = bsum + SCAN_B;           // SCAN_B
    int* csrcol = boff + SCAN_B;           // EE

    // ---- CSR build (real edges only; shared by both layers) ----
    hipMemsetAsync(deg, 0, (size_t)NN * sizeof(int), stream);
    hist_kernel<<<cdiv(EE, 256), 256, 0, stream>>>(ei, deg);
    block_sums<<<SCAN_B, 256, 0, stream>>>(deg, bsum);
    scan_bsums<<<1, 256, 0, stream>>>(bsum, boff, rowptr);
    scan_final<<<SCAN_B, 256, 0, stream>>>(deg, boff, rowptr, cursor);
    fill_kernel<<<cdiv(EE, 256), 256, 0, stream>>>(ei, cursor, csrcol);

    // ---- layer 1 ----
    gemm1_kernel<<<cdiv(NN, 64), 256, 0, stream>>>(x, W1, asr1, ads1, h1, as1, ad1);
    gat1_gather<<<cdiv(NN, 4), 256, 0, stream>>>(rowptr, csrcol, as1, ad1, h1, b1, z1);

    // ---- layer 2 ----
    gemm2_kernel<<<cdiv(NN, 64), 256, 0, stream>>>(z1, W2, asr2, ads2, h1, as2, ad2);
    gat2_gather<<<cdiv(NN, 4), 256, 0, stream>>>(rowptr, csrcol, as2, ad2, h1, b2, z2);

    // ---- link-prediction logits ----
    logits_kernel<<<cdiv((long long)2 * ETEST * 16, 256), 256, 0, stream>>>(pos, neg, z2, out);
}

// Round 7
// 260.388 us; speedup vs baseline: 1.2794x; 1.2794x over previous
//
#include <hip/hip_runtime.h>
#include <math.h>

#define NN 50000
#define FIN 128
#define EE 800000            // CSR holds only real edges; self-loops handled analytically
#define ETEST 100000
#define NEG_SLOPE 0.2f
#define NB 196               // buckets = ceil(NN/256); bucket = dst>>8
#define BB 256               // binning blocks
#define EPB 3125             // edges per binning block = EE/BB
#define M  (NB * BB)         // cnt/off table size = 50176
#define MB 196               // scan blocks for M = M/256
#define XP 68                // LDS pitch for transposed x tile
#define UG 16                // gather unroll width (predicated)

static inline int cdiv(long long a, int b) { return (int)((a + b - 1) / b); }

// ---------------- CSR build via bucketed partition (no global atomics, local writes) ----------

// per-block histogram of dst>>8 -> cnt[bucket][block]
__global__ void count_kernel(const int* __restrict__ ei, int* __restrict__ cnt) {
    __shared__ int hist[NB];
    int tid = threadIdx.x, blk = blockIdx.x;
    for (int i = tid; i < NB; i += 256) hist[i] = 0;
    __syncthreads();
    int beg = blk * EPB, end = beg + EPB; if (end > EE) end = EE;
    for (int e = beg + tid; e < end; e += 256)
        atomicAdd(&hist[((unsigned)ei[EE + e]) >> 8], 1);
    __syncthreads();
    for (int b = tid; b < NB; b += 256) cnt[b * BB + blk] = hist[b];
}

// hierarchical exclusive scan of cnt[M] -> off[M]
__global__ void block_sums(const int* __restrict__ cnt, int* __restrict__ bsum) {
    int idx = blockIdx.x * 256 + threadIdx.x;
    int v = cnt[idx];
#pragma unroll
    for (int off = 32; off >= 1; off >>= 1) v += __shfl_xor(v, off, 64);
    __shared__ int ws[4];
    if ((threadIdx.x & 63) == 0) ws[threadIdx.x >> 6] = v;
    __syncthreads();
    if (threadIdx.x == 0) bsum[blockIdx.x] = ws[0] + ws[1] + ws[2] + ws[3];
}

__global__ void scan_bsums(const int* __restrict__ bsum, int* __restrict__ boff) {
    __shared__ int s[256];
    int t = threadIdx.x;
    int v = (t < MB) ? bsum[t] : 0;
    s[t] = v;
    __syncthreads();
#pragma unroll
    for (int off = 1; off < 256; off <<= 1) {
        int u = (t >= off) ? s[t - off] : 0;
        __syncthreads();
        s[t] += u;
        __syncthreads();
    }
    if (t < MB) boff[t] = s[t] - v;   // exclusive
}

__global__ void scan_final(const int* __restrict__ cnt, const int* __restrict__ boff,
                           int* __restrict__ off) {
    __shared__ int s[256];
    int t = threadIdx.x;
    int idx = blockIdx.x * 256 + t;
    int v = cnt[idx];
    s[t] = v;
    __syncthreads();
#pragma unroll
    for (int off2 = 1; off2 < 256; off2 <<= 1) {
        int u = (t >= off2) ? s[t - off2] : 0;
        __syncthreads();
        s[t] += u;
        __syncthreads();
    }
    off[idx] = boff[blockIdx.x] + s[t] - v;   // exclusive
}

// partition edges into bucket-grouped array; pack (dst<<16)|src (both < 2^16)
__global__ void bin_kernel(const int* __restrict__ ei, const int* __restrict__ off,
                           unsigned* __restrict__ binned) {
    __shared__ int cur[NB];
    int tid = threadIdx.x, blk = blockIdx.x;
    for (int b = tid; b < NB; b += 256) cur[b] = off[b * BB + blk];
    __syncthreads();
    int beg = blk * EPB, end = beg + EPB; if (end > EE) end = EE;
    for (int e = beg + tid; e < end; e += 256) {
        unsigned dst = (unsigned)ei[EE + e], src = (unsigned)ei[e];
        int b = dst >> 8;
        int r = atomicAdd(&cur[b], 1);
        binned[r] = (dst << 16) | src;     // block's writes: 196 short runs, L2-local
    }
}

// one block per bucket: exact CSR within bucket (rowptr + col), writes stay in a ~13KB region
__global__ void csr_kernel(const unsigned* __restrict__ binned, const int* __restrict__ off,
                           int* __restrict__ rowptr, int* __restrict__ col) {
    __shared__ int cnt[256], s[256], cur[256];
    int b = blockIdx.x, t = threadIdx.x;
    int start = off[b * BB];
    int end = (b + 1 < NB) ? off[(b + 1) * BB] : EE;
    cnt[t] = 0;
    __syncthreads();
    for (int i = start + t; i < end; i += 256)
        atomicAdd(&cnt[(binned[i] >> 16) & 255], 1);
    __syncthreads();
    int v = cnt[t];
    s[t] = v;
    __syncthreads();
#pragma unroll
    for (int off2 = 1; off2 < 256; off2 <<= 1) {
        int u = (t >= off2) ? s[t - off2] : 0;
        __syncthreads();
        s[t] += u;
        __syncthreads();
    }
    int excl = start + s[t] - v;
    int dst = b * 256 + t;
    if (dst < NN) rowptr[dst] = excl;
    if (b == NB - 1 && t == 0) rowptr[NN] = EE;
    cur[t] = excl;
    __syncthreads();
    for (int i = start + t; i < end; i += 256) {
        unsigned p = binned[i];
        int dl = (p >> 16) & 255;
        int r = atomicAdd(&cur[dl], 1);
        col[r] = (int)(p & 0xFFFFu);
    }
}

// ---------------- Register-tiled GEMMs (64x64 tile, 4x4 acc per lane) ----------------

// x[NN,128] @ W[128,64] -> h; fused per-head dots (H=8,C=8)
__global__ void __launch_bounds__(256) gemm1_kernel(
        const float* __restrict__ x, const float* __restrict__ W,
        const float* __restrict__ att_src, const float* __restrict__ att_dst,
        float* __restrict__ h, float* __restrict__ a_src, float* __restrict__ a_dst) {
    __shared__ __align__(16) float Ws[FIN * 64];     // 32 KB
    __shared__ __align__(16) float xs[32 * XP];      // 8.7 KB, transposed chunk [k][r]
    int tid = threadIdx.x;
    for (int i = tid; i < FIN * 64 / 4; i += 256)
        ((float4*)Ws)[i] = ((const float4*)W)[i];
    int B = blockIdx.x * 64;
    int wave = tid >> 6, lane = tid & 63;
    int rg = lane >> 4, cg = lane & 15;
    int rbase = wave * 16 + rg * 4;
    float acc[4][4] = {};
    for (int kc = 0; kc < FIN; kc += 32) {
        __syncthreads();
#pragma unroll
        for (int p = 0; p < 2; ++p) {
            int idx = p * 256 + tid;            // 0..511
            int r = idx >> 3;                   // 0..63
            int m = idx & 7;
            int row = B + r;
            float4 v = (row < NN) ? ((const float4*)(x + (size_t)row * FIN + kc))[m]
                                  : make_float4(0.f, 0.f, 0.f, 0.f);
            int c4 = m << 2;
            xs[(c4 + 0) * XP + r] = v.x;
            xs[(c4 + 1) * XP + r] = v.y;
            xs[(c4 + 2) * XP + r] = v.z;
            xs[(c4 + 3) * XP + r] = v.w;
        }
        __syncthreads();
#pragma unroll 4
        for (int k = 0; k < 32; ++k) {
            float4 w4 = *(const float4*)&Ws[(kc + k) * 64 + cg * 4];
            float4 x4 = *(const float4*)&xs[k * XP + rbase];
            acc[0][0] = fmaf(x4.x, w4.x, acc[0][0]); acc[0][1] = fmaf(x4.x, w4.y, acc[0][1]);
            acc[0][2] = fmaf(x4.x, w4.z, acc[0][2]); acc[0][3] = fmaf(x4.x, w4.w, acc[0][3]);
            acc[1][0] = fmaf(x4.y, w4.x, acc[1][0]); acc[1][1] = fmaf(x4.y, w4.y, acc[1][1]);
            acc[1][2] = fmaf(x4.y, w4.z, acc[1][2]); acc[1][3] = fmaf(x4.y, w4.w, acc[1][3]);
            acc[2][0] = fmaf(x4.z, w4.x, acc[2][0]); acc[2][1] = fmaf(x4.z, w4.y, acc[2][1]);
            acc[2][2] = fmaf(x4.z, w4.z, acc[2][2]); acc[2][3] = fmaf(x4.z, w4.w, acc[2][3]);
            acc[3][0] = fmaf(x4.w, w4.x, acc[3][0]); acc[3][1] = fmaf(x4.w, w4.y, acc[3][1]);
            acc[3][2] = fmaf(x4.w, w4.z, acc[3][2]); acc[3][3] = fmaf(x4.w, w4.w, acc[3][3]);
        }
    }
    float as0 = att_src[4 * cg + 0], as1 = att_src[4 * cg + 1],
          as2 = att_src[4 * cg + 2], as3 = att_src[4 * cg + 3];
    float ad0 = att_dst[4 * cg + 0], ad1 = att_dst[4 * cg + 1],
          ad2 = att_dst[4 * cg + 2], ad3 = att_dst[4 * cg + 3];
#pragma unroll
    for (int j = 0; j < 4; ++j) {
        int row = B + rbase + j;
        if (row >= NN) continue;
        float4 hv = make_float4(acc[j][0], acc[j][1], acc[j][2], acc[j][3]);
        *(float4*)(h + (size_t)row * 64 + cg * 4) = hv;
        float ps = fmaf(hv.x, as0, fmaf(hv.y, as1, fmaf(hv.z, as2, hv.w * as3)));
        float pd = fmaf(hv.x, ad0, fmaf(hv.y, ad1, fmaf(hv.z, ad2, hv.w * ad3)));
        ps += __shfl_xor(ps, 1, 64);
        pd += __shfl_xor(pd, 1, 64);
        if ((cg & 1) == 0) {
            a_src[row * 8 + (cg >> 1)] = ps;
            a_dst[row * 8 + (cg >> 1)] = pd;
        }
    }
}

// z[NN,64] @ W[64,64] -> h; fused dots (H=1,C=64)
__global__ void __launch_bounds__(256) gemm2_kernel(
        const float* __restrict__ z, const float* __restrict__ W,
        const float* __restrict__ att_src, const float* __restrict__ att_dst,
        float* __restrict__ h, float* __restrict__ a_src, float* __restrict__ a_dst) {
    __shared__ __align__(16) float Ws[64 * 64];      // 16 KB
    __shared__ __align__(16) float xs[64 * XP];      // 17.4 KB, transposed [k][r]
    int tid = threadIdx.x;
    for (int i = tid; i < 64 * 64 / 4; i += 256)
        ((float4*)Ws)[i] = ((const float4*)W)[i];
    int B = blockIdx.x * 64;
#pragma unroll
    for (int p = 0; p < 4; ++p) {
        int idx = p * 256 + tid;                // 0..1023
        int r = idx >> 4;
        int m = idx & 15;
        int row = B + r;
        float4 v = (row < NN) ? ((const float4*)(z + (size_t)row * 64))[m]
                              : make_float4(0.f, 0.f, 0.f, 0.f);
        int c4 = m << 2;
        xs[(c4 + 0) * XP + r] = v.x;
        xs[(c4 + 1) * XP + r] = v.y;
        xs[(c4 + 2) * XP + r] = v.z;
        xs[(c4 + 3) * XP + r] = v.w;
    }
    int wave = tid >> 6, lane = tid & 63;
    int rg = lane >> 4, cg = lane & 15;
    int rbase = wave * 16 + rg * 4;
    float acc[4][4] = {};
    __syncthreads();
#pragma unroll 4
    for (int k = 0; k < 64; ++k) {
        float4 w4 = *(const float4*)&Ws[k * 64 + cg * 4];
        float4 x4 = *(const float4*)&xs[k * XP + rbase];
        acc[0][0] = fmaf(x4.x, w4.x, acc[0][0]); acc[0][1] = fmaf(x4.x, w4.y, acc[0][1]);
        acc[0][2] = fmaf(x4.x, w4.z, acc[0][2]); acc[0][3] = fmaf(x4.x, w4.w, acc[0][3]);
        acc[1][0] = fmaf(x4.y, w4.x, acc[1][0]); acc[1][1] = fmaf(x4.y, w4.y, acc[1][1]);
        acc[1][2] = fmaf(x4.y, w4.z, acc[1][2]); acc[1][3] = fmaf(x4.y, w4.w, acc[1][3]);
        acc[2][0] = fmaf(x4.z, w4.x, acc[2][0]); acc[2][1] = fmaf(x4.z, w4.y, acc[2][1]);
        acc[2][2] = fmaf(x4.z, w4.z, acc[2][2]); acc[2][3] = fmaf(x4.z, w4.w, acc[2][3]);
        acc[3][0] = fmaf(x4.w, w4.x, acc[3][0]); acc[3][1] = fmaf(x4.w, w4.y, acc[3][1]);
        acc[3][2] = fmaf(x4.w, w4.z, acc[3][2]); acc[3][3] = fmaf(x4.w, w4.w, acc[3][3]);
    }
    float as0 = att_src[4 * cg + 0], as1 = att_src[4 * cg + 1],
          as2 = att_src[4 * cg + 2], as3 = att_src[4 * cg + 3];
    float ad0 = att_dst[4 * cg + 0], ad1 = att_dst[4 * cg + 1],
          ad2 = att_dst[4 * cg + 2], ad3 = att_dst[4 * cg + 3];
#pragma unroll
    for (int j = 0; j < 4; ++j) {
        int row = B + rbase + j;
        if (row >= NN) continue;
        float4 hv = make_float4(acc[j][0], acc[j][1], acc[j][2], acc[j][3]);
        *(float4*)(h + (size_t)row * 64 + cg * 4) = hv;
        float ps = fmaf(hv.x, as0, fmaf(hv.y, as1, fmaf(hv.z, as2, hv.w * as3)));
        float pd = fmaf(hv.x, ad0, fmaf(hv.y, ad1, fmaf(hv.z, ad2, hv.w * ad3)));
#pragma unroll
        for (int off = 8; off >= 1; off >>= 1) {
            ps += __shfl_xor(ps, off, 64);
            pd += __shfl_xor(pd, off, 64);
        }
        if (cg == 0) { a_src[row] = ps; a_dst[row] = pd; }
    }
}

// ---------------- Fused GAT aggregation: predicated 16-wide, self-loop analytic ----------------

__device__ __forceinline__ float lrelu(float a) { return a > 0.f ? a : NEG_SLOPE * a; }

// Layer 1: H=8, C=8. One wave per dst node; lane = h*8+c.
__global__ void gat1_gather(const int* __restrict__ rowptr, const int* __restrict__ col,
                            const float* __restrict__ asrc, const float* __restrict__ adst,
                            const float* __restrict__ hfeat, const float* __restrict__ bias,
                            float* __restrict__ z1) {
    int v = blockIdx.x * 4 + (threadIdx.x >> 6);
    if (v >= NN) return;
    int lane = threadIdx.x & 63;
    int h = lane >> 3;
    int beg = rowptr[v], end = rowptr[v + 1];
    float ad = adst[v * 8 + h];
    float eself = __expf(lrelu(asrc[v * 8 + h] + ad));
    float den = eself;
    float acc = eself * hfeat[(size_t)v * 64 + lane];
    for (int i = beg; i < end; i += UG) {
        int lim = end - i;
        int s[UG]; float a[UG], f[UG];
#pragma unroll
        for (int u = 0; u < UG; ++u) {
            int idx = (u < lim) ? i + u : end - 1;   // clamped lanes: broadcast line
            s[u] = col[idx];
        }
#pragma unroll
        for (int u = 0; u < UG; ++u) a[u] = asrc[s[u] * 8 + h] + ad;
#pragma unroll
        for (int u = 0; u < UG; ++u) f[u] = hfeat[(size_t)s[u] * 64 + lane];
#pragma unroll
        for (int u = 0; u < UG; ++u) {
            float e = (u < lim) ? __expf(lrelu(a[u])) : 0.f;
            den += e;
            acc = fmaf(e, f[u], acc);
        }
    }
    float o = acc / fmaxf(den, 1e-16f) + bias[lane];
    z1[(size_t)v * 64 + lane] = o > 0.f ? o : expm1f(o);   // fused ELU
}

// Layer 2: H=1, C=64.
__global__ void gat2_gather(const int* __restrict__ rowptr, const int* __restrict__ col,
                            const float* __restrict__ asrc, const float* __restrict__ adst,
                            const float* __restrict__ hfeat, const float* __restrict__ bias,
                            float* __restrict__ z2) {
    int v = blockIdx.x * 4 + (threadIdx.x >> 6);
    if (v >= NN) return;
    int lane = threadIdx.x & 63;
    int beg = rowptr[v], end = rowptr[v + 1];
    float ad = adst[v];
    float eself = __expf(lrelu(asrc[v] + ad));
    float den = eself;
    float acc = eself * hfeat[(size_t)v * 64 + lane];
    for (int i = beg; i < end; i += UG) {
        int lim = end - i;
        int s[UG]; float a[UG], f[UG];
#pragma unroll
        for (int u = 0; u < UG; ++u) {
            int idx = (u < lim) ? i + u : end - 1;
            s[u] = col[idx];
        }
#pragma unroll
        for (int u = 0; u < UG; ++u) a[u] = asrc[s[u]] + ad;
#pragma unroll
        for (int u = 0; u < UG; ++u) f[u] = hfeat[(size_t)s[u] * 64 + lane];
#pragma unroll
        for (int u = 0; u < UG; ++u) {
            float e = (u < lim) ? __expf(lrelu(a[u])) : 0.f;
            den += e;
            acc = fmaf(e, f[u], acc);
        }
    }
    z2[(size_t)v * 64 + lane] = acc / fmaxf(den, 1e-16f) + bias[lane];
}

// logits[i] = dot64(z2[a], z2[b]); 16 lanes per logit, float4 loads
__global__ void logits_kernel(const int* __restrict__ pos, const int* __restrict__ neg,
                              const float* __restrict__ z2, float* __restrict__ out) {
    int t = blockIdx.x * 256 + threadIdx.x;
    int i = t >> 4;
    if (i >= 2 * ETEST) return;
    int sub = t & 15;
    int a, b;
    if (i < ETEST) { a = pos[i]; b = pos[ETEST + i]; }
    else           { a = neg[i - ETEST]; b = neg[i]; }
    float4 va = ((const float4*)(z2 + (size_t)a * 64))[sub];
    float4 vb = ((const float4*)(z2 + (size_t)b * 64))[sub];
    float p = fmaf(va.x, vb.x, fmaf(va.y, vb.y, fmaf(va.z, vb.z, va.w * vb.w)));
#pragma unroll
    for (int off = 8; off >= 1; off >>= 1) p += __shfl_xor(p, off, 64);
    if (sub == 0) out[i] = p;
}

extern "C" void kernel_launch(void* const* d_in, const int* in_sizes, int n_in,
                              void* d_out, int out_size, void* d_ws, size_t ws_size,
                              hipStream_t stream) {
    const float* x    = (const float*)d_in[0];
    const int*   ei   = (const int*)d_in[1];
    const int*   pos  = (const int*)d_in[2];
    const int*   neg  = (const int*)d_in[3];
    const float* W1   = (const float*)d_in[4];
    const float* asr1 = (const float*)d_in[5];
    const float* ads1 = (const float*)d_in[6];
    const float* b1   = (const float*)d_in[7];
    const float* W2   = (const float*)d_in[8];
    const float* asr2 = (const float*)d_in[9];
    const float* ads2 = (const float*)d_in[10];
    const float* b2   = (const float*)d_in[11];
    float* out = (float*)d_out;

    float* ws  = (float*)d_ws;
    float* h1  = ws;                       // NN*64 (h of layer1, reused as h of layer2)
    float* z1  = h1 + (size_t)NN * 64;     // NN*64
    float* z2  = z1 + (size_t)NN * 64;     // NN*64
    float* as1 = z2 + (size_t)NN * 64;     // NN*8
    float* ad1 = as1 + (size_t)NN * 8;     // NN*8
    float* as2 = ad1 + (size_t)NN * 8;     // NN
    float* ad2 = as2 + NN;                 // NN
    int* cnt    = (int*)(ad2 + NN);        // M
    int* off    = cnt + M;                 // M
    int* bsum   = off + M;                 // MB
    int* boff   = bsum + MB;               // MB
    int* rowptr = boff + MB;               // NN+1
    unsigned* binned = (unsigned*)(rowptr + NN + 1);  // EE
    int* csrcol = (int*)(binned + EE);     // EE
    // total ≈ 10.3M f32 + 1.8M int ≈ 48 MB

    // ---- CSR build: count -> scan -> bin -> per-bucket CSR (no memsets needed) ----
    count_kernel<<<BB, 256, 0, stream>>>(ei, cnt);
    block_sums<<<MB, 256, 0, stream>>>(cnt, bsum);
    scan_bsums<<<1, 256, 0, stream>>>(bsum, boff);
    scan_final<<<MB, 256, 0, stream>>>(cnt, boff, off);
    bin_kernel<<<BB, 256, 0, stream>>>(ei, off, binned);
    csr_kernel<<<NB, 256, 0, stream>>>(binned, off, rowptr, csrcol);

    // ---- layer 1 ----
    gemm1_kernel<<<cdiv(NN, 64), 256, 0, stream>>>(x, W1, asr1, ads1, h1, as1, ad1);
    gat1_gather<<<cdiv(NN, 4), 256, 0, stream>>>(rowptr, csrcol, as1, ad1, h1, b1, z1);

    // ---- layer 2 ----
    gemm2_kernel<<<cdiv(NN, 64), 256, 0, stream>>>(z1, W2, asr2, ads2, h1, as2, ad2);
    gat2_gather<<<cdiv(NN, 4), 256, 0, stream>>>(rowptr, csrcol, as2, ad2, h1, b2, z2);

    // ---- link-prediction logits ----
    logits_kernel<<<cdiv((long long)2 * ETEST * 16, 256), 256, 0, stream>>>(pos, neg, z2, out);
}

// Round 8
// 234.575 us; speedup vs baseline: 1.4202x; 1.1100x over previous
//
#include <hip/hip_runtime.h>
#include <math.h>

#define NN 50000
#define FIN 128
#define EE 800000            // CSR holds only real edges; self-loops handled analytically
#define ETEST 100000
#define NEG_SLOPE 0.2f
#define NB 196               // buckets = ceil(NN/256); bucket = dst>>8
#define BB 256               // binning blocks
#define EPB 3125             // edges per binning block = EE/BB
#define M  (NB * BB)         // cnt/off table size = 50176
#define MB 196               // scan blocks for M = M/256
#define XP 68                // LDS pitch for transposed x tile

static inline int cdiv(long long a, int b) { return (int)((a + b - 1) / b); }

// ---------------- CSR build via bucketed partition (no global atomics, local writes) ----------

__global__ void count_kernel(const int* __restrict__ ei, int* __restrict__ cnt) {
    __shared__ int hist[NB];
    int tid = threadIdx.x, blk = blockIdx.x;
    for (int i = tid; i < NB; i += 256) hist[i] = 0;
    __syncthreads();
    int beg = blk * EPB, end = beg + EPB; if (end > EE) end = EE;
    for (int e = beg + tid; e < end; e += 256)
        atomicAdd(&hist[((unsigned)ei[EE + e]) >> 8], 1);
    __syncthreads();
    for (int b = tid; b < NB; b += 256) cnt[b * BB + blk] = hist[b];
}

__global__ void block_sums(const int* __restrict__ cnt, int* __restrict__ bsum) {
    int idx = blockIdx.x * 256 + threadIdx.x;
    int v = cnt[idx];
#pragma unroll
    for (int off = 32; off >= 1; off >>= 1) v += __shfl_xor(v, off, 64);
    __shared__ int ws[4];
    if ((threadIdx.x & 63) == 0) ws[threadIdx.x >> 6] = v;
    __syncthreads();
    if (threadIdx.x == 0) bsum[blockIdx.x] = ws[0] + ws[1] + ws[2] + ws[3];
}

__global__ void scan_bsums(const int* __restrict__ bsum, int* __restrict__ boff) {
    __shared__ int s[256];
    int t = threadIdx.x;
    int v = (t < MB) ? bsum[t] : 0;
    s[t] = v;
    __syncthreads();
#pragma unroll
    for (int off = 1; off < 256; off <<= 1) {
        int u = (t >= off) ? s[t - off] : 0;
        __syncthreads();
        s[t] += u;
        __syncthreads();
    }
    if (t < MB) boff[t] = s[t] - v;   // exclusive
}

__global__ void scan_final(const int* __restrict__ cnt, const int* __restrict__ boff,
                           int* __restrict__ off) {
    __shared__ int s[256];
    int t = threadIdx.x;
    int idx = blockIdx.x * 256 + t;
    int v = cnt[idx];
    s[t] = v;
    __syncthreads();
#pragma unroll
    for (int off2 = 1; off2 < 256; off2 <<= 1) {
        int u = (t >= off2) ? s[t - off2] : 0;
        __syncthreads();
        s[t] += u;
        __syncthreads();
    }
    off[idx] = boff[blockIdx.x] + s[t] - v;   // exclusive
}

__global__ void bin_kernel(const int* __restrict__ ei, const int* __restrict__ off,
                           unsigned* __restrict__ binned) {
    __shared__ int cur[NB];
    int tid = threadIdx.x, blk = blockIdx.x;
    for (int b = tid; b < NB; b += 256) cur[b] = off[b * BB + blk];
    __syncthreads();
    int beg = blk * EPB, end = beg + EPB; if (end > EE) end = EE;
    for (int e = beg + tid; e < end; e += 256) {
        unsigned dst = (unsigned)ei[EE + e], src = (unsigned)ei[e];
        int b = dst >> 8;
        int r = atomicAdd(&cur[b], 1);
        binned[r] = (dst << 16) | src;
    }
}

__global__ void csr_kernel(const unsigned* __restrict__ binned, const int* __restrict__ off,
                           int* __restrict__ rowptr, int* __restrict__ col) {
    __shared__ int cnt[256], s[256], cur[256];
    int b = blockIdx.x, t = threadIdx.x;
    int start = off[b * BB];
    int end = (b + 1 < NB) ? off[(b + 1) * BB] : EE;
    cnt[t] = 0;
    __syncthreads();
    for (int i = start + t; i < end; i += 256)
        atomicAdd(&cnt[(binned[i] >> 16) & 255], 1);
    __syncthreads();
    int v = cnt[t];
    s[t] = v;
    __syncthreads();
#pragma unroll
    for (int off2 = 1; off2 < 256; off2 <<= 1) {
        int u = (t >= off2) ? s[t - off2] : 0;
        __syncthreads();
        s[t] += u;
        __syncthreads();
    }
    int excl = start + s[t] - v;
    int dst = b * 256 + t;
    if (dst < NN) rowptr[dst] = excl;
    if (b == NB - 1 && t == 0) rowptr[NN] = EE;
    cur[t] = excl;
    __syncthreads();
    for (int i = start + t; i < end; i += 256) {
        unsigned p = binned[i];
        int dl = (p >> 16) & 255;
        int r = atomicAdd(&cur[dl], 1);
        col[r] = (int)(p & 0xFFFFu);
    }
}

// ---------------- Register-tiled GEMMs (64x64 tile, 4x4 acc per lane) ----------------

__global__ void __launch_bounds__(256) gemm1_kernel(
        const float* __restrict__ x, const float* __restrict__ W,
        const float* __restrict__ att_src, const float* __restrict__ att_dst,
        float* __restrict__ h, float* __restrict__ a_src, float* __restrict__ a_dst) {
    __shared__ __align__(16) float Ws[FIN * 64];     // 32 KB
    __shared__ __align__(16) float xs[32 * XP];      // 8.7 KB
    int tid = threadIdx.x;
    for (int i = tid; i < FIN * 64 / 4; i += 256)
        ((float4*)Ws)[i] = ((const float4*)W)[i];
    int B = blockIdx.x * 64;
    int wave = tid >> 6, lane = tid & 63;
    int rg = lane >> 4, cg = lane & 15;
    int rbase = wave * 16 + rg * 4;
    float acc[4][4] = {};
    for (int kc = 0; kc < FIN; kc += 32) {
        __syncthreads();
#pragma unroll
        for (int p = 0; p < 2; ++p) {
            int idx = p * 256 + tid;
            int r = idx >> 3;
            int m = idx & 7;
            int row = B + r;
            float4 v = (row < NN) ? ((const float4*)(x + (size_t)row * FIN + kc))[m]
                                  : make_float4(0.f, 0.f, 0.f, 0.f);
            int c4 = m << 2;
            xs[(c4 + 0) * XP + r] = v.x;
            xs[(c4 + 1) * XP + r] = v.y;
            xs[(c4 + 2) * XP + r] = v.z;
            xs[(c4 + 3) * XP + r] = v.w;
        }
        __syncthreads();
#pragma unroll 4
        for (int k = 0; k < 32; ++k) {
            float4 w4 = *(const float4*)&Ws[(kc + k) * 64 + cg * 4];
            float4 x4 = *(const float4*)&xs[k * XP + rbase];
            acc[0][0] = fmaf(x4.x, w4.x, acc[0][0]); acc[0][1] = fmaf(x4.x, w4.y, acc[0][1]);
            acc[0][2] = fmaf(x4.x, w4.z, acc[0][2]); acc[0][3] = fmaf(x4.x, w4.w, acc[0][3]);
            acc[1][0] = fmaf(x4.y, w4.x, acc[1][0]); acc[1][1] = fmaf(x4.y, w4.y, acc[1][1]);
            acc[1][2] = fmaf(x4.y, w4.z, acc[1][2]); acc[1][3] = fmaf(x4.y, w4.w, acc[1][3]);
            acc[2][0] = fmaf(x4.z, w4.x, acc[2][0]); acc[2][1] = fmaf(x4.z, w4.y, acc[2][1]);
            acc[2][2] = fmaf(x4.z, w4.z, acc[2][2]); acc[2][3] = fmaf(x4.z, w4.w, acc[2][3]);
            acc[3][0] = fmaf(x4.w, w4.x, acc[3][0]); acc[3][1] = fmaf(x4.w, w4.y, acc[3][1]);
            acc[3][2] = fmaf(x4.w, w4.z, acc[3][2]); acc[3][3] = fmaf(x4.w, w4.w, acc[3][3]);
        }
    }
    float as0 = att_src[4 * cg + 0], as1 = att_src[4 * cg + 1],
          as2 = att_src[4 * cg + 2], as3 = att_src[4 * cg + 3];
    float ad0 = att_dst[4 * cg + 0], ad1 = att_dst[4 * cg + 1],
          ad2 = att_dst[4 * cg + 2], ad3 = att_dst[4 * cg + 3];
#pragma unroll
    for (int j = 0; j < 4; ++j) {
        int row = B + rbase + j;
        if (row >= NN) continue;
        float4 hv = make_float4(acc[j][0], acc[j][1], acc[j][2], acc[j][3]);
        *(float4*)(h + (size_t)row * 64 + cg * 4) = hv;
        float ps = fmaf(hv.x, as0, fmaf(hv.y, as1, fmaf(hv.z, as2, hv.w * as3)));
        float pd = fmaf(hv.x, ad0, fmaf(hv.y, ad1, fmaf(hv.z, ad2, hv.w * ad3)));
        ps += __shfl_xor(ps, 1, 64);
        pd += __shfl_xor(pd, 1, 64);
        if ((cg & 1) == 0) {
            a_src[row * 8 + (cg >> 1)] = ps;
            a_dst[row * 8 + (cg >> 1)] = pd;
        }
    }
}

__global__ void __launch_bounds__(256) gemm2_kernel(
        const float* __restrict__ z, const float* __restrict__ W,
        const float* __restrict__ att_src, const float* __restrict__ att_dst,
        float* __restrict__ h, float* __restrict__ a_src, float* __restrict__ a_dst) {
    __shared__ __align__(16) float Ws[64 * 64];
    __shared__ __align__(16) float xs[64 * XP];
    int tid = threadIdx.x;
    for (int i = tid; i < 64 * 64 / 4; i += 256)
        ((float4*)Ws)[i] = ((const float4*)W)[i];
    int B = blockIdx.x * 64;
#pragma unroll
    for (int p = 0; p < 4; ++p) {
        int idx = p * 256 + tid;
        int r = idx >> 4;
        int m = idx & 15;
        int row = B + r;
        float4 v = (row < NN) ? ((const float4*)(z + (size_t)row * 64))[m]
                              : make_float4(0.f, 0.f, 0.f, 0.f);
        int c4 = m << 2;
        xs[(c4 + 0) * XP + r] = v.x;
        xs[(c4 + 1) * XP + r] = v.y;
        xs[(c4 + 2) * XP + r] = v.z;
        xs[(c4 + 3) * XP + r] = v.w;
    }
    int wave = tid >> 6, lane = tid & 63;
    int rg = lane >> 4, cg = lane & 15;
    int rbase = wave * 16 + rg * 4;
    float acc[4][4] = {};
    __syncthreads();
#pragma unroll 4
    for (int k = 0; k < 64; ++k) {
        float4 w4 = *(const float4*)&Ws[k * 64 + cg * 4];
        float4 x4 = *(const float4*)&xs[k * XP + rbase];
        acc[0][0] = fmaf(x4.x, w4.x, acc[0][0]); acc[0][1] = fmaf(x4.x, w4.y, acc[0][1]);
        acc[0][2] = fmaf(x4.x, w4.z, acc[0][2]); acc[0][3] = fmaf(x4.x, w4.w, acc[0][3]);
        acc[1][0] = fmaf(x4.y, w4.x, acc[1][0]); acc[1][1] = fmaf(x4.y, w4.y, acc[1][1]);
        acc[1][2] = fmaf(x4.y, w4.z, acc[1][2]); acc[1][3] = fmaf(x4.y, w4.w, acc[1][3]);
        acc[2][0] = fmaf(x4.z, w4.x, acc[2][0]); acc[2][1] = fmaf(x4.z, w4.y, acc[2][1]);
        acc[2][2] = fmaf(x4.z, w4.z, acc[2][2]); acc[2][3] = fmaf(x4.z, w4.w, acc[2][3]);
        acc[3][0] = fmaf(x4.w, w4.x, acc[3][0]); acc[3][1] = fmaf(x4.w, w4.y, acc[3][1]);
        acc[3][2] = fmaf(x4.w, w4.z, acc[3][2]); acc[3][3] = fmaf(x4.w, w4.w, acc[3][3]);
    }
    float as0 = att_src[4 * cg + 0], as1 = att_src[4 * cg + 1],
          as2 = att_src[4 * cg + 2], as3 = att_src[4 * cg + 3];
    float ad0 = att_dst[4 * cg + 0], ad1 = att_dst[4 * cg + 1],
          ad2 = att_dst[4 * cg + 2], ad3 = att_dst[4 * cg + 3];
#pragma unroll
    for (int j = 0; j < 4; ++j) {
        int row = B + rbase + j;
        if (row >= NN) continue;
        float4 hv = make_float4(acc[j][0], acc[j][1], acc[j][2], acc[j][3]);
        *(float4*)(h + (size_t)row * 64 + cg * 4) = hv;
        float ps = fmaf(hv.x, as0, fmaf(hv.y, as1, fmaf(hv.z, as2, hv.w * as3)));
        float pd = fmaf(hv.x, ad0, fmaf(hv.y, ad1, fmaf(hv.z, ad2, hv.w * ad3)));
#pragma unroll
        for (int off = 8; off >= 1; off >>= 1) {
            ps += __shfl_xor(ps, off, 64);
            pd += __shfl_xor(pd, off, 64);
        }
        if (cg == 0) { a_src[row] = ps; a_dst[row] = pd; }
    }
}

// ---------------- Fused GAT aggregation: scalarized edge loop ----------------
// lrelu(a) = max(a, 0.2a)  (valid for slope<1)

// Layer 1: H=8, C=8. Wave per node. Phase 1: lane = (edge j)*8+head, 8 edges/chunk.
// Phase 2: per edge, src row base via readlane->SGPR (saddr loads), e via bpermute.
__global__ void gat1_gather(const int* __restrict__ rowptr, const int* __restrict__ col,
                            const float* __restrict__ asrc, const float* __restrict__ adst,
                            const float* __restrict__ hfeat, const float* __restrict__ bias,
                            float* __restrict__ z1) {
    int v = blockIdx.x * 4 + (threadIdx.x >> 6);
    if (v >= NN) return;
    int lane = threadIdx.x & 63;
    int j = lane >> 3;              // edge slot (phase 1) == head for message (phase 2)
    int hh = lane & 7;              // head (phase 1 alpha layout)
    int beg = rowptr[v], end = rowptr[v + 1];
    float ad_a = adst[v * 8 + hh];
    // self-loop (message layout: head = lane>>3)
    float aself = asrc[v * 8 + j] + adst[v * 8 + j];
    float eself = __expf(fmaxf(aself, NEG_SLOPE * aself));
    float acc = eself * hfeat[(size_t)v * 64 + lane];
    float den_a = 0.f;              // alpha layout: per (j,hh)
    for (int i = beg; i < end; i += 8) {
        int lim = end - i;
        int idx = (j < lim) ? i + j : end - 1;
        int vs = col[idx];                              // s_j replicated over 8 head-lanes
        float a = asrc[vs * 8 + hh] + ad_a;
        float e = __expf(fmaxf(a, NEG_SLOPE * a));
        e = (j < lim) ? e : 0.f;
        den_a += e;
#pragma unroll
        for (int u = 0; u < 8; ++u) {
            int s_u = __builtin_amdgcn_readlane(vs, u * 8);         // SGPR
            float eb = __shfl(e, u * 8 + j, 64);                    // e[u, head=lane>>3]
            float f = hfeat[(size_t)s_u * 64 + lane];               // saddr + lane*4
            acc = fmaf(eb, f, acc);
        }
    }
    // den: sum over edge slots j (xor 8,16,32), then pick head = lane>>3
    den_a += __shfl_xor(den_a, 8, 64);
    den_a += __shfl_xor(den_a, 16, 64);
    den_a += __shfl_xor(den_a, 32, 64);
    float den = __shfl(den_a, j, 64) + eself;
    float o = acc / fmaxf(den, 1e-16f) + bias[lane];
    z1[(size_t)v * 64 + lane] = o > 0.f ? o : expm1f(o);   // fused ELU
}

// Layer 2: H=1, C=64. Phase 1: lane&15 = edge slot (16/chunk). Phase 2: scalar e + saddr row.
__global__ void gat2_gather(const int* __restrict__ rowptr, const int* __restrict__ col,
                            const float* __restrict__ asrc, const float* __restrict__ adst,
                            const float* __restrict__ hfeat, const float* __restrict__ bias,
                            float* __restrict__ z2) {
    int v = blockIdx.x * 4 + (threadIdx.x >> 6);
    if (v >= NN) return;
    int lane = threadIdx.x & 63;
    int j16 = lane & 15;
    int beg = rowptr[v], end = rowptr[v + 1];
    float ad = adst[v];
    float aself = asrc[v] + ad;
    float eself = __expf(fmaxf(aself, NEG_SLOPE * aself));
    float den = eself;
    float acc = eself * hfeat[(size_t)v * 64 + lane];
    for (int i = beg; i < end; i += 16) {
        int lim = end - i;
        int idx = (j16 < lim) ? i + j16 : end - 1;
        int vs = col[idx];
        float a = asrc[vs] + ad;
        float e = __expf(fmaxf(a, NEG_SLOPE * a));
        e = (j16 < lim) ? e : 0.f;
#pragma unroll
        for (int u = 0; u < 16; ++u) {
            int s_u = __builtin_amdgcn_readlane(vs, u);                              // SGPR
            float e_u = __int_as_float(__builtin_amdgcn_readlane(__float_as_int(e), u)); // SGPR
            float f = hfeat[(size_t)s_u * 64 + lane];
            den += e_u;
            acc = fmaf(e_u, f, acc);
        }
    }
    z2[(size_t)v * 64 + lane] = acc / fmaxf(den, 1e-16f) + bias[lane];
}

// logits[i] = dot64(z2[a], z2[b]); 16 lanes per logit, float4 loads
__global__ void logits_kernel(const int* __restrict__ pos, const int* __restrict__ neg,
                              const float* __restrict__ z2, float* __restrict__ out) {
    int t = blockIdx.x * 256 + threadIdx.x;
    int i = t >> 4;
    if (i >= 2 * ETEST) return;
    int sub = t & 15;
    int a, b;
    if (i < ETEST) { a = pos[i]; b = pos[ETEST + i]; }
    else           { a = neg[i - ETEST]; b = neg[i]; }
    float4 va = ((const float4*)(z2 + (size_t)a * 64))[sub];
    float4 vb = ((const float4*)(z2 + (size_t)b * 64))[sub];
    float p = fmaf(va.x, vb.x, fmaf(va.y, vb.y, fmaf(va.z, vb.z, va.w * vb.w)));
#pragma unroll
    for (int off = 8; off >= 1; off >>= 1) p += __shfl_xor(p, off, 64);
    if (sub == 0) out[i] = p;
}

extern "C" void kernel_launch(void* const* d_in, const int* in_sizes, int n_in,
                              void* d_out, int out_size, void* d_ws, size_t ws_size,
                              hipStream_t stream) {
    const float* x    = (const float*)d_in[0];
    const int*   ei   = (const int*)d_in[1];
    const int*   pos  = (const int*)d_in[2];
    const int*   neg  = (const int*)d_in[3];
    const float* W1   = (const float*)d_in[4];
    const float* asr1 = (const float*)d_in[5];
    const float* ads1 = (const float*)d_in[6];
    const float* b1   = (const float*)d_in[7];
    const float* W2   = (const float*)d_in[8];
    const float* asr2 = (const float*)d_in[9];
    const float* ads2 = (const float*)d_in[10];
    const float* b2   = (const float*)d_in[11];
    float* out = (float*)d_out;

    float* ws  = (float*)d_ws;
    float* h1  = ws;                       // NN*64
    float* z1  = h1 + (size_t)NN * 64;     // NN*64
    float* z2  = z1 + (size_t)NN * 64;     // NN*64
    float* as1 = z2 + (size_t)NN * 64;     // NN*8
    float* ad1 = as1 + (size_t)NN * 8;     // NN*8
    float* as2 = ad1 + (size_t)NN * 8;     // NN
    float* ad2 = as2 + NN;                 // NN
    int* cnt    = (int*)(ad2 + NN);        // M
    int* off    = cnt + M;                 // M
    int* bsum   = off + M;                 // MB
    int* boff   = bsum + MB;               // MB
    int* rowptr = boff + MB;               // NN+1
    unsigned* binned = (unsigned*)(rowptr + NN + 1);  // EE
    int* csrcol = (int*)(binned + EE);     // EE

    // ---- CSR build ----
    count_kernel<<<BB, 256, 0, stream>>>(ei, cnt);
    block_sums<<<MB, 256, 0, stream>>>(cnt, bsum);
    scan_bsums<<<1, 256, 0, stream>>>(bsum, boff);
    scan_final<<<MB, 256, 0, stream>>>(cnt, boff, off);
    bin_kernel<<<BB, 256, 0, stream>>>(ei, off, binned);
    csr_kernel<<<NB, 256, 0, stream>>>(binned, off, rowptr, csrcol);

    // ---- layer 1 ----
    gemm1_kernel<<<cdiv(NN, 64), 256, 0, stream>>>(x, W1, asr1, ads1, h1, as1, ad1);
    gat1_gather<<<cdiv(NN, 4), 256, 0, stream>>>(rowptr, csrcol, as1, ad1, h1, b1, z1);

    // ---- layer 2 ----
    gemm2_kernel<<<cdiv(NN, 64), 256, 0, stream>>>(z1, W2, asr2, ads2, h1, as2, ad2);
    gat2_gather<<<cdiv(NN, 4), 256, 0, stream>>>(rowptr, csrcol, as2, ad2, h1, b2, z2);

    // ---- link-prediction logits ----
    logits_kernel<<<cdiv((long long)2 * ETEST * 16, 256), 256, 0, stream>>>(pos, neg, z2, out);
}